// Round 6
// baseline (225.042 us; speedup 1.0000x reference)
//
#include <hip/hip_runtime.h>
#include <hip/hip_bf16.h>

// Shapes (fixed by the reference)
#define NB 8
#define ND 512
#define NL 2048
#define NH 8
#define NDH 64
#define VROWS 72   // V head rows: 64 V + 1 mask row (+7 don't-care rows)

typedef __attribute__((ext_vector_type(8))) short bf16x8;
typedef __attribute__((ext_vector_type(4))) float f32x4;
typedef __attribute__((ext_vector_type(4))) unsigned int u32x4;

__device__ __forceinline__ unsigned short f2bf(float x) {
    return (unsigned short)((__float_as_uint(x) + 0x8000u) >> 16);
}

__device__ __forceinline__ float exp2_fast(float x) {
#if __has_builtin(__builtin_amdgcn_exp2f)
    return __builtin_amdgcn_exp2f(x);
#else
    return exp2f(x);
#endif
}

// pack bf16(a) | bf16(b)<<16 : 2 rounding adds + 1 v_perm_b32
__device__ __forceinline__ unsigned int pack_bf16(float a, float b) {
    unsigned int ua = __float_as_uint(a) + 0x8000u;
    unsigned int ub = __float_as_uint(b) + 0x8000u;
    return __builtin_amdgcn_perm(ub, ua, 0x07060302u);
}

// async global->LDS, 16 B per lane; lds base wave-uniform, lane i -> lds+i*16.
__device__ __forceinline__ void async16(void* lds, const void* g) {
    __builtin_amdgcn_global_load_lds(
        (const __attribute__((address_space(1))) unsigned int*)g,
        (__attribute__((address_space(3))) unsigned int*)lds, 16, 0, 0);
}

// ---------------------------------------------------------------------------
// prep_small: fused convert_w (blocks 0..383) + V mask row (blocks 384..447).
// Wcat bf16 [1536][512] = [w_mem ; w_q * 0.125 * log2(e)] (softmax in exp2
// domain). Vt row 64 = key-permuted mask (1/0 bf16); the PV MFMA then
// computes lsum for free. Rows 65..71 left as poison: they only feed
// accumulator elements that are never read.
// ---------------------------------------------------------------------------
__global__ __launch_bounds__(256) void prep_small(
    const float* __restrict__ w_mem, const float* __restrict__ w_q,
    const int* __restrict__ maskp,
    unsigned short* __restrict__ Wc, unsigned short* __restrict__ Vt)
{
    const int bid = blockIdx.x;
    if (bid < 384) {
        int idx = (bid * 256 + threadIdx.x) * 8;
        int o = idx >> 9, k = idx & 511;
        const float* src;
        float sc;
        if (o < 1024) { src = w_mem + (size_t)o * ND + k; sc = 1.0f; }
        else          { src = w_q + (size_t)(o - 1024) * ND + k;
                        sc = 0.125f * 1.4426950408889634f; }
        float4 f0 = *(const float4*)src;
        float4 f1 = *(const float4*)(src + 4);
        ushort4 p0 = { f2bf(f0.x * sc), f2bf(f0.y * sc), f2bf(f0.z * sc), f2bf(f0.w * sc) };
        ushort4 p1 = { f2bf(f1.x * sc), f2bf(f1.y * sc), f2bf(f1.z * sc), f2bf(f1.w * sc) };
        *(ushort4*)(Wc + idx) = p0;
        *(ushort4*)(Wc + idx + 4) = p1;
    } else {
        const int bh = bid - 384;
        const int b = bh >> 3;
        unsigned short* row64 = Vt + ((size_t)bh * VROWS + 64) * NL;
        for (int kk = threadIdx.x; kk < NL; kk += 256) {
            int s = (kk & 32) | ((kk & 12) << 1) | ((kk & 16) >> 2) | (kk & 3);
            row64[(kk & ~63) | s] =
                maskp[b * NL + kk] ? (unsigned short)0x3F80 : (unsigned short)0;
        }
    }
}

// ---------------------------------------------------------------------------
// convert_xt: Xt bf16 [b][l][d]  <-  queries fp32 [b][d][l]  (LDS transpose).
// ---------------------------------------------------------------------------
__global__ __launch_bounds__(256) void convert_xt(
    const float* __restrict__ qin, unsigned short* __restrict__ Xt)
{
    __shared__ __align__(16) unsigned short T[64][72];
    const int b = blockIdx.z, d0 = blockIdx.y * 64, l0 = blockIdx.x * 64;
    const int t = threadIdx.x;
    const float* X = qin + ((size_t)b * ND + d0) * NL + l0;
    #pragma unroll
    for (int i = 0; i < 4; ++i) {
        int e = t + i * 256;
        int d = e >> 4, l4 = (e & 15) * 4;
        float4 v = *(const float4*)(X + (size_t)d * NL + l4);
        T[l4 + 0][d] = f2bf(v.x);
        T[l4 + 1][d] = f2bf(v.y);
        T[l4 + 2][d] = f2bf(v.z);
        T[l4 + 3][d] = f2bf(v.w);
    }
    __syncthreads();
    #pragma unroll
    for (int i = 0; i < 2; ++i) {
        int e = t + i * 256;
        int row = e >> 3, c8 = (e & 7) * 8;
        *(bf16x8*)(Xt + ((size_t)b * NL + l0 + row) * ND + d0 + c8) =
            *(const bf16x8*)&T[row][c8];
    }
}

// ---------------------------------------------------------------------------
// proj_mfma: C[o][l] = sum_k Wc[o][k] * Xt[b][l][k].
// async global_load_lds staging, XOR-swizzled unpadded LDS (conflict-free).
// K/Q regions: standard operand order, ushort4 stores along dh.
// V region: SWAPPED operands (C rows = l) -> ushort4 stores along l (the key
// permutation preserves 4-contiguity since kk&3 -> s&3). V cols pre-zeroed
// by mask (masked keys contribute nothing in attention).
// ---------------------------------------------------------------------------
__global__ __launch_bounds__(256, 3) void proj_mfma(
    const unsigned short* __restrict__ Wc,
    const unsigned short* __restrict__ Xt,
    const int* __restrict__ maskp,
    unsigned short* __restrict__ Kh,
    unsigned short* __restrict__ Qh,
    unsigned short* __restrict__ Vt)
{
    __shared__ __align__(16) unsigned short As[128 * 64];
    __shared__ __align__(16) unsigned short Bs[128 * 64];

    const int b  = blockIdx.z;
    const int m0 = blockIdx.y * 128;
    const int n0 = blockIdx.x * 128;
    const int t  = threadIdx.x;
    const int w = t >> 6, lane = t & 63, quad = lane >> 4, lq = lane & 15;
    const int wo = (w >> 1) * 64, wl = (w & 1) * 64;
    const int lr = lane >> 3;
    const int cbsw = (lane & 7) ^ lr;
    const bool isV = (m0 >= 512) && (m0 < 1024);
    const f32x4 z4 = {0.f, 0.f, 0.f, 0.f};

    f32x4 acc[4][4];
    #pragma unroll
    for (int im = 0; im < 4; ++im)
        #pragma unroll
        for (int in = 0; in < 4; ++in) acc[im][in] = z4;

    const int sw[2] = {(quad ^ (lq & 7)) * 8, ((4 + quad) ^ (lq & 7)) * 8};

    for (int k0 = 0; k0 < ND; k0 += 64) {
        __syncthreads();
        #pragma unroll 2
        for (int i = w; i < 32; i += 4) {
            if (i < 16) {
                int R = i * 8;
                async16(&As[R * 64],
                        Wc + (size_t)(m0 + R + lr) * ND + k0 + cbsw * 8);
            } else {
                int R = (i - 16) * 8;
                async16(&Bs[R * 64],
                        Xt + ((size_t)b * NL + n0 + R + lr) * ND + k0 + cbsw * 8);
            }
        }
        __syncthreads();

        #pragma unroll
        for (int ks = 0; ks < 2; ++ks) {
            bf16x8 af[4], bfr[4];
            #pragma unroll
            for (int im = 0; im < 4; ++im)
                af[im] = *(const bf16x8*)&As[(wo + im * 16 + lq) * 64 + sw[ks]];
            #pragma unroll
            for (int in = 0; in < 4; ++in)
                bfr[in] = *(const bf16x8*)&Bs[(wl + in * 16 + lq) * 64 + sw[ks]];
            if (!isV) {
                #pragma unroll
                for (int im = 0; im < 4; ++im)
                    #pragma unroll
                    for (int in = 0; in < 4; ++in)
                        acc[im][in] = __builtin_amdgcn_mfma_f32_16x16x32_bf16(
                            af[im], bfr[in], acc[im][in], 0, 0, 0);
            } else {
                // swapped: acc[im = l-subtile][in = dh-subtile]
                #pragma unroll
                for (int im = 0; im < 4; ++im)
                    #pragma unroll
                    for (int in = 0; in < 4; ++in)
                        acc[im][in] = __builtin_amdgcn_mfma_f32_16x16x32_bf16(
                            bfr[im], af[in], acc[im][in], 0, 0, 0);
            }
        }
    }

    if (!isV) {
        unsigned short* dst = (m0 < 512) ? Kh : Qh;
        #pragma unroll
        for (int im = 0; im < 4; ++im) {
            int o  = (m0 + wo + im * 16 + quad * 4) & 511;
            int hh = o >> 6, dh = o & 63;
            #pragma unroll
            for (int in = 0; in < 4; ++in) {
                int l = n0 + wl + in * 16 + lq;
                ushort4 pk = { f2bf(acc[im][in][0]), f2bf(acc[im][in][1]),
                               f2bf(acc[im][in][2]), f2bf(acc[im][in][3]) };
                *(ushort4*)&dst[(((size_t)b * NH + hh) * NL + l) * NDH + dh] = pk;
            }
        }
    } else {
        #pragma unroll
        for (int im = 0; im < 4; ++im) {
            int l4 = n0 + wl + im * 16 + quad * 4;      // 4 consecutive l
            int kk = l4 & 63;
            int s4 = (kk & 32) | ((kk & 12) << 1) | ((kk & 16) >> 2);
            int lp = (l4 & ~63) | s4;
            int4 m4 = *(const int4*)&maskp[b * NL + l4];
            float mv[4] = {(float)m4.x, (float)m4.y, (float)m4.z, (float)m4.w};
            #pragma unroll
            for (int in = 0; in < 4; ++in) {
                int o  = m0 - 512 + wo + in * 16 + lq;  // 0..511
                int hh = o >> 6, dd = o & 63;
                ushort4 pk = { f2bf(acc[im][in][0] * mv[0]),
                               f2bf(acc[im][in][1] * mv[1]),
                               f2bf(acc[im][in][2] * mv[2]),
                               f2bf(acc[im][in][3] * mv[3]) };
                *(ushort4*)&Vt[(((size_t)(b * NH + hh)) * VROWS + dd) * NL + lp] = pk;
            }
        }
    }
}

// ---------------------------------------------------------------------------
// attn_mfma v4: as v3 (async dbuf staging, register-only P via key-permuted
// V, mask-row lsum, exp2 softmax) plus: k-loop unrolled x2 (compile-time
// buffer pointers -> LDS addresses loop-invariant) and sacc assigned on the
// first k-step (no per-tile accumulator zero-init).
// ---------------------------------------------------------------------------
__global__ __launch_bounds__(256, 2) void attn_mfma(
    const unsigned short* __restrict__ Qh,
    const unsigned short* __restrict__ Kh,
    const unsigned short* __restrict__ Vt,
    float* __restrict__ out)
{
    __shared__ __align__(16) unsigned short Ks2[2][64 * 64];
    __shared__ __align__(16) unsigned short Vs2[2][80 * 64];

    const int id = blockIdx.x;
    const int h  = id & 7;                 // XCD swizzle: same h -> same XCD
    const int b  = (id >> 3) & 7;
    const int q0 = (id >> 6) * 256;
    const int t = threadIdx.x;
    const int w = t >> 6, lane = t & 63, quad = lane >> 4, lq = lane & 15;
    const int lr = lane >> 3;
    const int cbsw = (lane & 7) ^ lr;
    const f32x4 z4 = {0.f, 0.f, 0.f, 0.f};

    const unsigned short* Qg = Qh + ((size_t)(b * NH + h)) * NL * NDH;
    const unsigned short* Kg = Kh + ((size_t)(b * NH + h)) * NL * NDH;
    const unsigned short* Vg = Vt + ((size_t)(b * NH + h)) * VROWS * NL;

    const int sw[2] = {(quad ^ (lq & 7)) * 8, ((4 + quad) ^ (lq & 7)) * 8};

    auto stage = [&](unsigned short* Kd, unsigned short* Vd, int kn) {
        #pragma unroll 2
        for (int i = w; i < 17; i += 4) {
            if (i < 8) {
                int R = i * 8;
                async16(Kd + R * 64, Kg + (size_t)(kn + R + lr) * NDH + cbsw * 8);
            } else {
                int R = (i - 8) * 8;
                async16(Vd + R * 64, Vg + (size_t)(R + lr) * NL + kn + cbsw * 8);
            }
        }
    };

    // ---- stage tile 0; Q fragments straight to registers meanwhile ----
    stage(Ks2[0], Vs2[0], 0);

    bf16x8 qf[4][2];
    #pragma unroll
    for (int ni = 0; ni < 4; ++ni)
        #pragma unroll
        for (int ks = 0; ks < 2; ++ks)
            qf[ni][ks] = *(const bf16x8*)
                &Qg[(size_t)(q0 + w * 64 + ni * 16 + lq) * NDH + ks * 32 + quad * 8];

    f32x4 oacc[5][4];
    #pragma unroll
    for (int dm = 0; dm < 5; ++dm)
        #pragma unroll
        for (int ni = 0; ni < 4; ++ni) oacc[dm][ni] = z4;

    auto body = [&](const unsigned short* KsB, const unsigned short* VsB,
                    unsigned short* KsN, unsigned short* VsN,
                    int kn, bool pf) {
        __syncthreads();          // drains DMA for KsB/VsB; frees KsN/VsN
        if (pf) stage(KsN, VsN, kn);

        // ---- S^T = K Q^T (log2 units); first k-step assigns ----
        f32x4 sacc[4][4];
        {
            bf16x8 kf[4];
            #pragma unroll
            for (int mi = 0; mi < 4; ++mi)
                kf[mi] = *(const bf16x8*)&KsB[(mi * 16 + lq) * 64 + sw[0]];
            #pragma unroll
            for (int mi = 0; mi < 4; ++mi)
                #pragma unroll
                for (int ni = 0; ni < 4; ++ni)
                    sacc[mi][ni] = __builtin_amdgcn_mfma_f32_16x16x32_bf16(
                        kf[mi], qf[ni][0], z4, 0, 0, 0);
            #pragma unroll
            for (int mi = 0; mi < 4; ++mi)
                kf[mi] = *(const bf16x8*)&KsB[(mi * 16 + lq) * 64 + sw[1]];
            #pragma unroll
            for (int mi = 0; mi < 4; ++mi)
                #pragma unroll
                for (int ni = 0; ni < 4; ++ni)
                    sacc[mi][ni] = __builtin_amdgcn_mfma_f32_16x16x32_bf16(
                        kf[mi], qf[ni][1], sacc[mi][ni], 0, 0, 0);
        }

        // ---- p = exp2(s); pack into PV B-fragments (registers only) ----
        u32x4 pfu[4][2];
        #pragma unroll
        for (int mi = 0; mi < 4; ++mi) {
            const int ks = mi >> 1, jp = (mi & 1) * 2;
            #pragma unroll
            for (int ni = 0; ni < 4; ++ni) {
                float e0 = exp2_fast(sacc[mi][ni][0]);
                float e1 = exp2_fast(sacc[mi][ni][1]);
                float e2 = exp2_fast(sacc[mi][ni][2]);
                float e3 = exp2_fast(sacc[mi][ni][3]);
                pfu[ni][ks][jp + 0] = pack_bf16(e0, e1);
                pfu[ni][ks][jp + 1] = pack_bf16(e2, e3);
            }
        }

        // ---- O^T += V^T P^T ; dm=4 row (mask row) accumulates lsum ----
        #pragma unroll
        for (int ks = 0; ks < 2; ++ks) {
            bf16x8 vf[5];
            #pragma unroll
            for (int dm = 0; dm < 5; ++dm)
                vf[dm] = *(const bf16x8*)&VsB[(dm * 16 + lq) * 64 + sw[ks]];
            #pragma unroll
            for (int dm = 0; dm < 5; ++dm)
                #pragma unroll
                for (int ni = 0; ni < 4; ++ni)
                    oacc[dm][ni] = __builtin_amdgcn_mfma_f32_16x16x32_bf16(
                        vf[dm], __builtin_bit_cast(bf16x8, pfu[ni][ks]),
                        oacc[dm][ni], 0, 0, 0);
        }
    };

    for (int k0 = 0; k0 < NL; k0 += 128) {
        body(Ks2[0], Vs2[0], Ks2[1], Vs2[1], k0 + 64, true);
        body(Ks2[1], Vs2[1], Ks2[0], Vs2[0], k0 + 128, k0 + 128 < NL);
    }

    // ---- epilogue: lsum lives in oacc[4][ni][0] on quad-0 lanes ----
    float inv[4];
    #pragma unroll
    for (int ni = 0; ni < 4; ++ni)
        inv[ni] = 1.0f / __shfl(oacc[4][ni][0], lq);

    #pragma unroll
    for (int dm = 0; dm < 4; ++dm)
        #pragma unroll
        for (int ni = 0; ni < 4; ++ni)
            #pragma unroll
            for (int r = 0; r < 4; ++r) {
                int dh = dm * 16 + quad * 4 + r;
                int l  = q0 + w * 64 + ni * 16 + lq;
                out[((size_t)b * ND + h * NDH + dh) * NL + l] =
                    oacc[dm][ni][r] * inv[ni];
            }
}

extern "C" void kernel_launch(void* const* d_in, const int* in_sizes, int n_in,
                              void* d_out, int out_size, void* d_ws, size_t ws_size,
                              hipStream_t stream) {
    const float* queries = (const float*)d_in[0];
    const int*   maskp   = (const int*)d_in[1];
    const float* w_mem   = (const float*)d_in[2];
    const float* w_q     = (const float*)d_in[3];
    float* out = (float*)d_out;

    const size_t headElems  = (size_t)NB * NH * NL * NDH;    // 8.39M
    const size_t vElems     = (size_t)NB * NH * VROWS * NL;  // 9.44M
    unsigned short* Kh = (unsigned short*)d_ws;
    unsigned short* Vt = Kh + headElems;
    unsigned short* Qh = Vt + vElems;
    unsigned short* Wc = Qh + headElems;                     // 1536*512
    unsigned short* Xt = Wc + (size_t)1536 * ND;             // 8*2048*512
    // total ws use: ~71 MB

    prep_small<<<448, 256, 0, stream>>>(w_mem, w_q, maskp, Wc, Vt);

    dim3 gx(NL / 64, ND / 64, NB);     // (32, 8, 8)
    convert_xt<<<gx, 256, 0, stream>>>(queries, Xt);

    dim3 g1(NL / 128, 1536 / 128, NB); // (16, 12, 8)
    proj_mfma<<<g1, 256, 0, stream>>>(Wc, Xt, maskp, Kh, Qh, Vt);

    attn_mfma<<<512, 256, 0, stream>>>(Qh, Kh, Vt, out);
}

// Round 7
// 190.318 us; speedup vs baseline: 1.1825x; 1.1825x over previous
//
#include <hip/hip_runtime.h>
#include <hip/hip_bf16.h>

// Shapes (fixed by the reference)
#define NB 8
#define ND 512
#define NL 2048
#define NH 8
#define NDH 64
#define VROWS 72   // V head rows: 64 V + 1 mask row (+7 don't-care rows)

typedef __attribute__((ext_vector_type(8))) short bf16x8;
typedef __attribute__((ext_vector_type(4))) float f32x4;
typedef __attribute__((ext_vector_type(4))) unsigned int u32x4;

__device__ __forceinline__ unsigned short f2bf(float x) {
    return (unsigned short)((__float_as_uint(x) + 0x8000u) >> 16);
}

__device__ __forceinline__ float exp2_fast(float x) {
#if __has_builtin(__builtin_amdgcn_exp2f)
    return __builtin_amdgcn_exp2f(x);
#else
    return exp2f(x);
#endif
}

// pack bf16(a) | bf16(b)<<16
__device__ __forceinline__ unsigned int pack_bf16(float a, float b) {
#if __has_builtin(__builtin_amdgcn_cvt_pk_bf16_f32)
    auto r = __builtin_amdgcn_cvt_pk_bf16_f32(a, b);
    unsigned int u;
    __builtin_memcpy(&u, &r, 4);
    return u;
#else
    unsigned int ua = __float_as_uint(a) + 0x8000u;
    unsigned int ub = __float_as_uint(b) + 0x8000u;
    return __builtin_amdgcn_perm(ub, ua, 0x07060302u);
#endif
}

// async global->LDS, 16 B per lane; lds base wave-uniform, lane i -> lds+i*16.
__device__ __forceinline__ void async16(void* lds, const void* g) {
    __builtin_amdgcn_global_load_lds(
        (const __attribute__((address_space(1))) unsigned int*)g,
        (__attribute__((address_space(3))) unsigned int*)lds, 16, 0, 0);
}

// ---------------------------------------------------------------------------
// prep: fused convert_xt (blocks 0..2047) + convert_w (2048..2431) +
// V mask row (2432..2495).
//   Xt bf16 [b][l][d] <- queries fp32 [b][d][l] (LDS transpose)
//   Wc bf16 [1536][512] = [w_mem ; w_q * 0.125 * log2(e)]
//   Vt row 64 = key-permuted mask (1/0 bf16) -> PV MFMA computes lsum free.
// ---------------------------------------------------------------------------
__global__ __launch_bounds__(256) void prep(
    const float* __restrict__ qin,
    const float* __restrict__ w_mem, const float* __restrict__ w_q,
    const int* __restrict__ maskp,
    unsigned short* __restrict__ Xt, unsigned short* __restrict__ Wc,
    unsigned short* __restrict__ Vt)
{
    const int bid = blockIdx.x;
    const int t = threadIdx.x;
    if (bid < 2048) {
        __shared__ __align__(16) unsigned short T[64][72];
        const int l0 = (bid & 31) * 64, d0 = ((bid >> 5) & 7) * 64, b = bid >> 8;
        const float* X = qin + ((size_t)b * ND + d0) * NL + l0;
        #pragma unroll
        for (int i = 0; i < 4; ++i) {
            int e = t + i * 256;
            int d = e >> 4, l4 = (e & 15) * 4;
            float4 v = *(const float4*)(X + (size_t)d * NL + l4);
            T[l4 + 0][d] = f2bf(v.x);
            T[l4 + 1][d] = f2bf(v.y);
            T[l4 + 2][d] = f2bf(v.z);
            T[l4 + 3][d] = f2bf(v.w);
        }
        __syncthreads();
        #pragma unroll
        for (int i = 0; i < 2; ++i) {
            int e = t + i * 256;
            int row = e >> 3, c8 = (e & 7) * 8;
            *(bf16x8*)(Xt + ((size_t)b * NL + l0 + row) * ND + d0 + c8) =
                *(const bf16x8*)&T[row][c8];
        }
    } else if (bid < 2432) {
        int idx = ((bid - 2048) * 256 + t) * 8;
        int o = idx >> 9, k = idx & 511;
        const float* src;
        float sc;
        if (o < 1024) { src = w_mem + (size_t)o * ND + k; sc = 1.0f; }
        else          { src = w_q + (size_t)(o - 1024) * ND + k;
                        sc = 0.125f * 1.4426950408889634f; }
        float4 f0 = *(const float4*)src;
        float4 f1 = *(const float4*)(src + 4);
        ushort4 p0 = { f2bf(f0.x * sc), f2bf(f0.y * sc), f2bf(f0.z * sc), f2bf(f0.w * sc) };
        ushort4 p1 = { f2bf(f1.x * sc), f2bf(f1.y * sc), f2bf(f1.z * sc), f2bf(f1.w * sc) };
        *(ushort4*)(Wc + idx) = p0;
        *(ushort4*)(Wc + idx + 4) = p1;
    } else {
        const int bh = bid - 2432;
        const int b = bh >> 3;
        unsigned short* row64 = Vt + ((size_t)bh * VROWS + 64) * NL;
        for (int kk = t; kk < NL; kk += 256) {
            int s = (kk & 32) | ((kk & 12) << 1) | ((kk & 16) >> 2) | (kk & 3);
            row64[(kk & ~63) | s] =
                maskp[b * NL + kk] ? (unsigned short)0x3F80 : (unsigned short)0;
        }
    }
}

// ---------------------------------------------------------------------------
// proj_mfma: C[o][l] = sum_k Wc[o][k] * Xt[b][l][k].
// async global_load_lds staging, XOR-swizzled unpadded LDS (conflict-free).
// isV hoisted OUT of the K-loop (round-6 in-loop branch caused a ~20 us
// regression): two full K-loops, block-uniform selection.
// K/Q: ushort4 stores along dh. V: swapped operands -> ushort4 along l
// (key permutation preserves 4-contiguity), mask folded (masked V cols = 0).
// ---------------------------------------------------------------------------
__global__ __launch_bounds__(256, 3) void proj_mfma(
    const unsigned short* __restrict__ Wc,
    const unsigned short* __restrict__ Xt,
    const int* __restrict__ maskp,
    unsigned short* __restrict__ Kh,
    unsigned short* __restrict__ Qh,
    unsigned short* __restrict__ Vt)
{
    __shared__ __align__(16) unsigned short As[128 * 64];
    __shared__ __align__(16) unsigned short Bs[128 * 64];

    const int b  = blockIdx.z;
    const int m0 = blockIdx.y * 128;
    const int n0 = blockIdx.x * 128;
    const int t  = threadIdx.x;
    const int w = t >> 6, lane = t & 63, quad = lane >> 4, lq = lane & 15;
    const int wo = (w >> 1) * 64, wl = (w & 1) * 64;
    const int lr = lane >> 3;
    const int cbsw = (lane & 7) ^ lr;
    const bool isV = (m0 >= 512) && (m0 < 1024);
    const f32x4 z4 = {0.f, 0.f, 0.f, 0.f};
    const int sw[2] = {(quad ^ (lq & 7)) * 8, ((4 + quad) ^ (lq & 7)) * 8};

    f32x4 acc[4][4];
    #pragma unroll
    for (int im = 0; im < 4; ++im)
        #pragma unroll
        for (int in = 0; in < 4; ++in) acc[im][in] = z4;

    if (!isV) {
        for (int k0 = 0; k0 < ND; k0 += 64) {
            __syncthreads();
            #pragma unroll 2
            for (int i = w; i < 32; i += 4) {
                if (i < 16) {
                    int R = i * 8;
                    async16(&As[R * 64],
                            Wc + (size_t)(m0 + R + lr) * ND + k0 + cbsw * 8);
                } else {
                    int R = (i - 16) * 8;
                    async16(&Bs[R * 64],
                            Xt + ((size_t)b * NL + n0 + R + lr) * ND + k0 + cbsw * 8);
                }
            }
            __syncthreads();
            #pragma unroll
            for (int ks = 0; ks < 2; ++ks) {
                bf16x8 af[4], bfr[4];
                #pragma unroll
                for (int im = 0; im < 4; ++im)
                    af[im] = *(const bf16x8*)&As[(wo + im * 16 + lq) * 64 + sw[ks]];
                #pragma unroll
                for (int in = 0; in < 4; ++in)
                    bfr[in] = *(const bf16x8*)&Bs[(wl + in * 16 + lq) * 64 + sw[ks]];
                #pragma unroll
                for (int im = 0; im < 4; ++im)
                    #pragma unroll
                    for (int in = 0; in < 4; ++in)
                        acc[im][in] = __builtin_amdgcn_mfma_f32_16x16x32_bf16(
                            af[im], bfr[in], acc[im][in], 0, 0, 0);
            }
        }
        unsigned short* dst = (m0 < 512) ? Kh : Qh;
        #pragma unroll
        for (int im = 0; im < 4; ++im) {
            int o  = (m0 + wo + im * 16 + quad * 4) & 511;
            int hh = o >> 6, dh = o & 63;
            #pragma unroll
            for (int in = 0; in < 4; ++in) {
                int l = n0 + wl + in * 16 + lq;
                ushort4 pk = { f2bf(acc[im][in][0]), f2bf(acc[im][in][1]),
                               f2bf(acc[im][in][2]), f2bf(acc[im][in][3]) };
                *(ushort4*)&dst[(((size_t)b * NH + hh) * NL + l) * NDH + dh] = pk;
            }
        }
    } else {
        for (int k0 = 0; k0 < ND; k0 += 64) {
            __syncthreads();
            #pragma unroll 2
            for (int i = w; i < 32; i += 4) {
                if (i < 16) {
                    int R = i * 8;
                    async16(&As[R * 64],
                            Wc + (size_t)(m0 + R + lr) * ND + k0 + cbsw * 8);
                } else {
                    int R = (i - 16) * 8;
                    async16(&Bs[R * 64],
                            Xt + ((size_t)b * NL + n0 + R + lr) * ND + k0 + cbsw * 8);
                }
            }
            __syncthreads();
            #pragma unroll
            for (int ks = 0; ks < 2; ++ks) {
                bf16x8 af[4], bfr[4];
                #pragma unroll
                for (int im = 0; im < 4; ++im)
                    af[im] = *(const bf16x8*)&As[(wo + im * 16 + lq) * 64 + sw[ks]];
                #pragma unroll
                for (int in = 0; in < 4; ++in)
                    bfr[in] = *(const bf16x8*)&Bs[(wl + in * 16 + lq) * 64 + sw[ks]];
                // swapped: acc[im = l-subtile][in = dh-subtile]
                #pragma unroll
                for (int im = 0; im < 4; ++im)
                    #pragma unroll
                    for (int in = 0; in < 4; ++in)
                        acc[im][in] = __builtin_amdgcn_mfma_f32_16x16x32_bf16(
                            bfr[im], af[in], acc[im][in], 0, 0, 0);
            }
        }
        #pragma unroll
        for (int im = 0; im < 4; ++im) {
            int l4 = n0 + wl + im * 16 + quad * 4;      // 4 consecutive l
            int kk = l4 & 63;
            int s4 = (kk & 32) | ((kk & 12) << 1) | ((kk & 16) >> 2);
            int lp = (l4 & ~63) | s4;
            int4 m4 = *(const int4*)&maskp[b * NL + l4];
            float mv[4] = {(float)m4.x, (float)m4.y, (float)m4.z, (float)m4.w};
            #pragma unroll
            for (int in = 0; in < 4; ++in) {
                int o  = m0 - 512 + wo + in * 16 + lq;  // 0..511
                int hh = o >> 6, dd = o & 63;
                ushort4 pk = { f2bf(acc[im][in][0] * mv[0]),
                               f2bf(acc[im][in][1] * mv[1]),
                               f2bf(acc[im][in][2] * mv[2]),
                               f2bf(acc[im][in][3] * mv[3]) };
                *(ushort4*)&Vt[(((size_t)(b * NH + hh)) * VROWS + dd) * NL + lp] = pk;
            }
        }
    }
}

// ---------------------------------------------------------------------------
// attn_mfma v5: 512-thread blocks (8 waves x 32 q-rows = 256-row tile),
// grid 512 -> 2 blocks/CU -> 4 waves/SIMD (was 2): hides exp2 chains,
// MFMA-read hazards, barrier convoy. Async dbuf K/V staging (1-2 DMA/wave),
// register-only P (key-permuted V), mask-row lsum, exp2 softmax, pack via
// v_cvt_pk_bf16_f32 when available. exp/pack per ks-half so sacc halves die
// early (VGPR <= 128 for the 4-waves/SIMD cap).
// ---------------------------------------------------------------------------
__global__ __launch_bounds__(512, 4) void attn_mfma(
    const unsigned short* __restrict__ Qh,
    const unsigned short* __restrict__ Kh,
    const unsigned short* __restrict__ Vt,
    float* __restrict__ out)
{
    __shared__ __align__(16) unsigned short Ks2[2][64 * 64];  // 16 KB
    __shared__ __align__(16) unsigned short Vs2[2][80 * 64];  // 20 KB (72..79 junk-read)

    const int id = blockIdx.x;
    const int h  = id & 7;                 // XCD swizzle: same h -> same XCD
    const int b  = (id >> 3) & 7;
    const int q0 = (id >> 6) * 256;
    const int t = threadIdx.x;             // 0..511
    const int w = t >> 6;                  // 0..7
    const int lane = t & 63, quad = lane >> 4, lq = lane & 15;
    const int lr = lane >> 3;
    const int cbsw = (lane & 7) ^ lr;
    const f32x4 z4 = {0.f, 0.f, 0.f, 0.f};

    const unsigned short* Qg = Qh + ((size_t)(b * NH + h)) * NL * NDH;
    const unsigned short* Kg = Kh + ((size_t)(b * NH + h)) * NL * NDH;
    const unsigned short* Vg = Vt + ((size_t)(b * NH + h)) * VROWS * NL;

    const int sw0 = (quad ^ (lq & 7)) * 8;
    const int sw1 = ((4 + quad) ^ (lq & 7)) * 8;

    // incremental staging pointers (wave w stages K rows 8w..8w+7, V rows
    // 8w..8w+7; wave 7 also V rows 64..71 = mask row group)
    const unsigned short* kgp = Kg + (size_t)(w * 8 + lr) * NDH + cbsw * 8;
    const unsigned short* vgp = Vg + (size_t)(w * 8 + lr) * NL + cbsw * 8;
    const unsigned short* vgm = Vg + (size_t)(64 + lr) * NL + cbsw * 8;

    auto stage = [&](unsigned short* Kd, unsigned short* Vd, int kn) {
        async16(Kd + w * 512, kgp + (size_t)kn * NDH);
        async16(Vd + w * 512, vgp + kn);
        if (w == 7) async16(Vd + 8 * 512, vgm + kn);
    };

    // ---- stage tile 0; Q fragments straight to registers meanwhile ----
    stage(Ks2[0], Vs2[0], 0);

    bf16x8 qf[2][2];
    #pragma unroll
    for (int ni = 0; ni < 2; ++ni)
        #pragma unroll
        for (int ks = 0; ks < 2; ++ks)
            qf[ni][ks] = *(const bf16x8*)
                &Qg[(size_t)(q0 + w * 32 + ni * 16 + lq) * NDH + ks * 32 + quad * 8];

    f32x4 oacc[5][2];
    #pragma unroll
    for (int dm = 0; dm < 5; ++dm)
        #pragma unroll
        for (int ni = 0; ni < 2; ++ni) oacc[dm][ni] = z4;

    auto body = [&](const unsigned short* KsB, const unsigned short* VsB,
                    unsigned short* KsN, unsigned short* VsN,
                    int kn, bool pf) {
        __syncthreads();          // drains DMA for KsB/VsB; frees KsN/VsN
        if (pf) stage(KsN, VsN, kn);

        const unsigned short* kb0 = KsB + lq * 64 + sw0;
        const unsigned short* kb1 = KsB + lq * 64 + sw1;
        const unsigned short* vb0 = VsB + lq * 64 + sw0;
        const unsigned short* vb1 = VsB + lq * 64 + sw1;

        // ---- S^T = K Q^T (log2 units); first k-step assigns ----
        f32x4 sacc[4][2];
        #pragma unroll
        for (int mi = 0; mi < 4; ++mi) {
            bf16x8 kf = *(const bf16x8*)&kb0[mi * 1024];
            sacc[mi][0] = __builtin_amdgcn_mfma_f32_16x16x32_bf16(kf, qf[0][0], z4, 0, 0, 0);
            sacc[mi][1] = __builtin_amdgcn_mfma_f32_16x16x32_bf16(kf, qf[1][0], z4, 0, 0, 0);
        }
        #pragma unroll
        for (int mi = 0; mi < 4; ++mi) {
            bf16x8 kf = *(const bf16x8*)&kb1[mi * 1024];
            sacc[mi][0] = __builtin_amdgcn_mfma_f32_16x16x32_bf16(kf, qf[0][1], sacc[mi][0], 0, 0, 0);
            sacc[mi][1] = __builtin_amdgcn_mfma_f32_16x16x32_bf16(kf, qf[1][1], sacc[mi][1], 0, 0, 0);
        }

        // ---- per ks-half: p = exp2(s), pack, PV MFMA ----
        #pragma unroll
        for (int ks = 0; ks < 2; ++ks) {
            u32x4 pfu[2];
            #pragma unroll
            for (int half = 0; half < 2; ++half) {
                const int mi = ks * 2 + half, jp = half * 2;
                #pragma unroll
                for (int ni = 0; ni < 2; ++ni) {
                    float e0 = exp2_fast(sacc[mi][ni][0]);
                    float e1 = exp2_fast(sacc[mi][ni][1]);
                    float e2 = exp2_fast(sacc[mi][ni][2]);
                    float e3 = exp2_fast(sacc[mi][ni][3]);
                    pfu[ni][jp + 0] = pack_bf16(e0, e1);
                    pfu[ni][jp + 1] = pack_bf16(e2, e3);
                }
            }
            const unsigned short* vb = ks ? vb1 : vb0;
            #pragma unroll
            for (int dm = 0; dm < 5; ++dm) {
                bf16x8 vf = *(const bf16x8*)&vb[dm * 1024];
                oacc[dm][0] = __builtin_amdgcn_mfma_f32_16x16x32_bf16(
                    vf, __builtin_bit_cast(bf16x8, pfu[0]), oacc[dm][0], 0, 0, 0);
                oacc[dm][1] = __builtin_amdgcn_mfma_f32_16x16x32_bf16(
                    vf, __builtin_bit_cast(bf16x8, pfu[1]), oacc[dm][1], 0, 0, 0);
            }
        }
    };

    for (int k0 = 0; k0 < NL; k0 += 128) {
        body(Ks2[0], Vs2[0], Ks2[1], Vs2[1], k0 + 64, true);
        body(Ks2[1], Vs2[1], Ks2[0], Vs2[0], k0 + 128, k0 + 128 < NL);
    }

    // ---- epilogue: lsum lives in oacc[4][ni][0] on quad-0 lanes ----
    float inv[2];
    #pragma unroll
    for (int ni = 0; ni < 2; ++ni)
        inv[ni] = 1.0f / __shfl(oacc[4][ni][0], lq);

    #pragma unroll
    for (int dm = 0; dm < 4; ++dm)
        #pragma unroll
        for (int ni = 0; ni < 2; ++ni)
            #pragma unroll
            for (int r = 0; r < 4; ++r) {
                int dh = dm * 16 + quad * 4 + r;
                int l  = q0 + w * 32 + ni * 16 + lq;
                out[((size_t)b * ND + h * NDH + dh) * NL + l] =
                    oacc[dm][ni][r] * inv[ni];
            }
}

extern "C" void kernel_launch(void* const* d_in, const int* in_sizes, int n_in,
                              void* d_out, int out_size, void* d_ws, size_t ws_size,
                              hipStream_t stream) {
    const float* queries = (const float*)d_in[0];
    const int*   maskp   = (const int*)d_in[1];
    const float* w_mem   = (const float*)d_in[2];
    const float* w_q     = (const float*)d_in[3];
    float* out = (float*)d_out;

    const size_t headElems  = (size_t)NB * NH * NL * NDH;    // 8.39M
    const size_t vElems     = (size_t)NB * NH * VROWS * NL;  // 9.44M
    unsigned short* Kh = (unsigned short*)d_ws;
    unsigned short* Vt = Kh + headElems;
    unsigned short* Qh = Vt + vElems;
    unsigned short* Wc = Qh + headElems;                     // 1536*512
    unsigned short* Xt = Wc + (size_t)1536 * ND;             // 8*2048*512
    // total ws use: ~71 MB

    prep<<<2496, 256, 0, stream>>>(queries, w_mem, w_q, maskp, Xt, Wc, Vt);

    dim3 g1(NL / 128, 1536 / 128, NB); // (16, 12, 8)
    proj_mfma<<<g1, 256, 0, stream>>>(Wc, Xt, maskp, Kh, Qh, Vt);

    attn_mfma<<<512, 512, 0, stream>>>(Qh, Kh, Vt, out);
}